// Round 14
// baseline (601.514 us; speedup 1.0000x reference)
//
#include <hip/hip_runtime.h>

#define B_ 64
#define S_ 512
#define D_ 256
#define H_ 128
#define M_ 64
#define N_ (B_ * S_)                 // 32768 nodes
#define YSZ ((size_t)N_ * H_)        // 4194304 floats
#define ADJSZ ((size_t)B_ * S_ * S_) // 16777216 floats

typedef __attribute__((ext_vector_type(8))) _Float16 f16x8;
typedef __attribute__((ext_vector_type(2))) _Float16 h2;
typedef __attribute__((ext_vector_type(4))) float f32x4;

#define MFMAH(a, b, c) __builtin_amdgcn_mfma_f32_16x16x32_f16(a, b, c, 0, 0, 0)

// LDS-only barrier (k2): __syncthreads() drains vmcnt(0) too.
#define BARL() asm volatile("s_waitcnt lgkmcnt(0)\n\ts_barrier" ::: "memory")

#if __has_builtin(__builtin_amdgcn_fdot2)
#define FDOT2(a, b, c) __builtin_amdgcn_fdot2((a), (b), (c), false)
#else
__device__ __forceinline__ float FDOT2(h2 a, h2 b, float c) {
  return c + (float)a.x * (float)b.x + (float)a.y * (float)b.y;
}
#endif

// weight frag store: 8 n-tiles x 14 k-chunks, 64 lanes x 16B each (f16)
#define WFRAGS (8 * 14)
#define WBYTES ((size_t)WFRAGS * 64 * 16)  // 114688

// Clamp-free: e^{2x} overflow -> rcp(inf)=0 -> tanh=+1 exactly; e->0 -> -1.
__device__ __forceinline__ float fast_tanh(float x) {
  float e = __builtin_amdgcn_exp2f(x * 2.8853900817779268f);
  float r = __builtin_amdgcn_rcpf(e + 1.0f);
  return fmaf(-2.0f, r, 1.0f);
}
__device__ __forceinline__ float fast_sigmoid(float x) {
  float e = __builtin_amdgcn_exp2f(x * -1.4426950408889634f);
  return __builtin_amdgcn_rcpf(1.0f + e);
}

// element index in a [rows][Kc] f16 array, XOR-swizzled 16B (8-elem) granules
__device__ __forceinline__ int sw(int row, int col, int Kc) {
  return row * Kc + ((((col >> 3) ^ (row & 7)) << 3) | (col & 7));
}
// granule-index form for [16][128] state arrays (g = 8-elem granule 0..15)
__device__ __forceinline__ int swu(int row, int g) {
  return row * 128 + (((g ^ (row & 7)) << 3));
}

__device__ __forceinline__ f16x8 pack8(float4 a, float4 b) {
  f16x8 r;
  r[0] = (_Float16)a.x; r[1] = (_Float16)a.y;
  r[2] = (_Float16)a.z; r[3] = (_Float16)a.w;
  r[4] = (_Float16)b.x; r[5] = (_Float16)b.y;
  r[6] = (_Float16)b.z; r[7] = (_Float16)b.w;
  return r;
}

// ---------------- K0: pack f16 weight fragments (native MFMA frag order;
// layout is symmetric for A and B operands: row/col = lane&15, k=(lane>>4)*8)
__global__ __launch_bounds__(256) void k0_prep(
    const float* __restrict__ eWih0, const float* __restrict__ eWhh0,
    const float* __restrict__ eWih1, const float* __restrict__ eWhh1,
    unsigned short* __restrict__ Wf) {
  int t = blockIdx.x * 256 + threadIdx.x;
  if (t >= WFRAGS * 64) return;
  int fid = t >> 6, lane = t & 63;
  int ntg = fid / 14, kc = fid % 14;
  int j = ntg * 16 + (lane & 15);
  int kbase = (kc < 6 ? kc : kc - 6) * 32 + (lane >> 4) * 8;
  unsigned pk[4];
#pragma unroll
  for (int ii = 0; ii < 4; ++ii) {
    unsigned p2 = 0;
#pragma unroll
    for (int s = 0; s < 2; ++s) {
      int k = kbase + ii * 2 + s;
      float wv;
      if (kc < 6)
        wv = (k < 64) ? eWih0[j * 64 + k] : eWhh0[j * 128 + (k - 64)];
      else
        wv = (k < 128) ? eWih1[j * 128 + k] : eWhh1[j * 128 + (k - 128)];
      _Float16 h = (_Float16)wv;
      unsigned short us = *(unsigned short*)&h;
      p2 |= ((unsigned)us) << (16 * s);
    }
    pk[ii] = p2;
  }
  ((uint4*)Wf)[fid * 64 + lane] = make_uint4(pk[0], pk[1], pk[2], pk[3]);
}

// ------------------------------------------- K1: P0 = x @ Wih0^T + (bih0+bhh0)
__global__ __launch_bounds__(256) void k1_gemm(
    const float* __restrict__ x, const float* __restrict__ W,
    const float* __restrict__ bih, const float* __restrict__ bhh,
    float* __restrict__ P0) {
  __shared__ float Xs[32][132];
  __shared__ float Ws[32][132];
  const int t = threadIdx.x;
  const int ty = t >> 4, tx = t & 15;
  const int n0 = blockIdx.x * 128;
  float acc[8][8];
#pragma unroll
  for (int i = 0; i < 8; ++i)
#pragma unroll
    for (int j = 0; j < 8; ++j) acc[i][j] = 0.f;

  for (int kc = 0; kc < 256; kc += 32) {
    __syncthreads();
#pragma unroll
    for (int l = 0; l < 4; ++l) {
      int idx = t + l * 256;
      int r = idx >> 3, f4 = idx & 7;
      float4 v = *(const float4*)&x[(size_t)(n0 + r) * 256 + kc + f4 * 4];
      Xs[f4 * 4 + 0][r] = v.x; Xs[f4 * 4 + 1][r] = v.y;
      Xs[f4 * 4 + 2][r] = v.z; Xs[f4 * 4 + 3][r] = v.w;
      float4 wv = *(const float4*)&W[(size_t)r * 256 + kc + f4 * 4];
      Ws[f4 * 4 + 0][r] = wv.x; Ws[f4 * 4 + 1][r] = wv.y;
      Ws[f4 * 4 + 2][r] = wv.z; Ws[f4 * 4 + 3][r] = wv.w;
    }
    __syncthreads();
#pragma unroll
    for (int kk = 0; kk < 32; ++kk) {
      float4 xa = *(const float4*)&Xs[kk][ty * 8];
      float4 xb = *(const float4*)&Xs[kk][ty * 8 + 4];
      float4 wa = *(const float4*)&Ws[kk][tx * 8];
      float4 wb = *(const float4*)&Ws[kk][tx * 8 + 4];
      float xr[8] = {xa.x, xa.y, xa.z, xa.w, xb.x, xb.y, xb.z, xb.w};
      float wr[8] = {wa.x, wa.y, wa.z, wa.w, wb.x, wb.y, wb.z, wb.w};
#pragma unroll
      for (int i = 0; i < 8; ++i)
#pragma unroll
        for (int j = 0; j < 8; ++j) acc[i][j] += xr[i] * wr[j];
    }
  }
  float bias[8];
#pragma unroll
  for (int j = 0; j < 8; ++j) bias[j] = bih[tx * 8 + j] + bhh[tx * 8 + j];
#pragma unroll
  for (int i = 0; i < 8; ++i) {
    float4 s0 = make_float4(acc[i][0] + bias[0], acc[i][1] + bias[1],
                            acc[i][2] + bias[2], acc[i][3] + bias[3]);
    float4 s1 = make_float4(acc[i][4] + bias[4], acc[i][5] + bias[5],
                            acc[i][6] + bias[6], acc[i][7] + bias[7]);
    size_t base = (size_t)(n0 + ty * 8 + i) * 128 + tx * 8;
    *(float4*)&P0[base] = s0;
    *(float4*)&P0[base + 4] = s1;
  }
}

// ------------------------- K2 v10: batched-MFMA graph RNN, 8 waves; waves
// 0-3 = L0, 4-7 = L1 pipelined; 1 LDS-only barrier/step. v10: L1's 8-deep
// dependent MFMA chain split into 2 accumulators (4+4), reads kept inline.
#define K2STEP(S, PP)                                                         \
  {                                                                           \
    if (isL0 && (S) < 512) {                                                  \
      const int rd0 = ((S)&1) ^ 1;                                            \
      f32x4 acc[2];                                                           \
      _Pragma("unroll") for (int i = 0; i < 2; ++i)                           \
          acc[i] = __builtin_bit_cast(f32x4, PP[i]);                          \
      _Pragma("unroll") for (int kc = 0; kc < 4; ++kc) {                      \
        f16x8 bf = *(const f16x8*)&h0s[rd0][swu(colB, kc * 4 + q)];           \
        _Pragma("unroll") for (int i = 0; i < 2; ++i)                         \
            acc[i] = MFMAH(WA[i][kc], bf, acc[i]);                            \
      }                                                                       \
      int tn = ((S) + 2 < 512) ? (S) + 2 : 511;                               \
      _Pragma("unroll") for (int i = 0; i < 2; ++i)                           \
          PP[i] = *(const float4*)(p0base[i] + (size_t)tn * 128);             \
      _Pragma("unroll") for (int i = 0; i < 2; ++i) {                         \
        float v0 = fast_tanh(acc[i][0]), v1 = fast_tanh(acc[i][1]);           \
        float v2 = fast_tanh(acc[i][2]), v3 = fast_tanh(acc[i][3]);           \
        int nb = (wl * 2 + i) * 16 + q * 4;                                   \
        int g = nb >> 3;                                                      \
        int idx = colB * 128 + (((g ^ (colB & 7)) << 3) | (nb & 7));          \
        h2 lo = {(_Float16)v0, (_Float16)v1};                                 \
        h2 hi = {(_Float16)v2, (_Float16)v3};                                 \
        uint2 u = {__builtin_bit_cast(unsigned, lo),                          \
                   __builtin_bit_cast(unsigned, hi)};                         \
        *(uint2*)&h0s[(S)&1][idx] = u;                                        \
      }                                                                       \
    } else if (!isL0 && (S) >= 1) {                                           \
      const int t = (S)-1;                                                    \
      const int rb = t & 1;                                                   \
      f32x4 acc[2], accB[2];                                                  \
      _Pragma("unroll") for (int i = 0; i < 2; ++i) {                         \
        acc[i] = b1v[i];                                                      \
        accB[i] = (f32x4){0.f, 0.f, 0.f, 0.f};                                \
      }                                                                       \
      _Pragma("unroll") for (int kc = 0; kc < 4; ++kc) {                      \
        f16x8 bf = *(const f16x8*)&h0s[rb][swu(colB, kc * 4 + q)];            \
        if ((kc & 1) == 0) {                                                  \
          _Pragma("unroll") for (int i = 0; i < 2; ++i)                       \
              acc[i] = MFMAH(WA[i][kc], bf, acc[i]);                          \
        } else {                                                              \
          _Pragma("unroll") for (int i = 0; i < 2; ++i)                       \
              accB[i] = MFMAH(WA[i][kc], bf, accB[i]);                        \
        }                                                                     \
      }                                                                       \
      _Pragma("unroll") for (int kc = 0; kc < 4; ++kc) {                      \
        f16x8 bf = *(const f16x8*)&h1s[rb ^ 1][swu(colB, kc * 4 + q)];        \
        if ((kc & 1) == 0) {                                                  \
          _Pragma("unroll") for (int i = 0; i < 2; ++i)                       \
              acc[i] = MFMAH(WB[i][kc], bf, acc[i]);                          \
        } else {                                                              \
          _Pragma("unroll") for (int i = 0; i < 2; ++i)                       \
              accB[i] = MFMAH(WB[i][kc], bf, accB[i]);                        \
        }                                                                     \
      }                                                                       \
      float m = mk[colB][t];                                                  \
      _Pragma("unroll") for (int i = 0; i < 2; ++i) {                         \
        f32x4 at = acc[i] + accB[i];                                          \
        float v0 = fast_tanh(at[0]), v1 = fast_tanh(at[1]);                   \
        float v2 = fast_tanh(at[2]), v3 = fast_tanh(at[3]);                   \
        int nb = (wl * 2 + i) * 16 + q * 4;                                   \
        int g = nb >> 3;                                                      \
        int idx = colB * 128 + (((g ^ (colB & 7)) << 3) | (nb & 7));          \
        h2 lo = {(_Float16)v0, (_Float16)v1};                                 \
        h2 hi = {(_Float16)v2, (_Float16)v3};                                 \
        uint2 u = {__builtin_bit_cast(unsigned, lo),                          \
                   __builtin_bit_cast(unsigned, hi)};                         \
        *(uint2*)&h1s[rb][idx] = u;                                           \
        float4 yv = {v0 * m, v1 * m, v2 * m, v3 * m};                         \
        *(float4*)&Y[((size_t)(b0 + colB) * 512 + t) * 128 + nb] = yv;        \
      }                                                                       \
    }                                                                         \
    BARL();                                                                   \
  }

__global__ __launch_bounds__(512, 1) void k2_v10(
    const float* __restrict__ P0, const float* __restrict__ Whh0,
    const float* __restrict__ Wih1, const float* __restrict__ Whh1,
    const float* __restrict__ bih1, const float* __restrict__ bhh1,
    const int* __restrict__ mask, float* __restrict__ Y) {
  __shared__ _Float16 h0s[2][16 * 128];
  __shared__ _Float16 h1s[2][16 * 128];
  __shared__ float mk[16][516];  // padded stride
  const int tid = threadIdx.x;
  const int w = tid >> 6, l = tid & 63;
  const int b0 = blockIdx.x * 16;
  const int colB = l & 15;
  const int q = l >> 4;
  const bool isL0 = (w < 4);
  const int wl = isL0 ? w : (w - 4);

  for (int i = tid; i < 16 * 512; i += 512) {
    int bb = i >> 9, t = i & 511;
    mk[bb][t] = (float)mask[(b0 + bb) * 512 + t];
  }
  for (int i = tid; i < 1024; i += 512) {
    ((unsigned*)&h0s[1][0])[i] = 0u;
    ((unsigned*)&h1s[1][0])[i] = 0u;
  }

  f16x8 WA[2][4];  // L0: Whh0 ; L1: Wih1
  f16x8 WB[2][4];  // L1 only: Whh1
  {
    const float* src = isL0 ? Whh0 : Wih1;
#pragma unroll
    for (int i = 0; i < 2; ++i)
#pragma unroll
      for (int kc = 0; kc < 4; ++kc) {
        const float* r =
            src + ((wl * 2 + i) * 16 + colB) * 128 + kc * 32 + q * 8;
        WA[i][kc] = pack8(*(const float4*)r, *(const float4*)(r + 4));
      }
    if (!isL0) {
#pragma unroll
      for (int i = 0; i < 2; ++i)
#pragma unroll
        for (int kc = 0; kc < 4; ++kc) {
          const float* r =
              Whh1 + ((wl * 2 + i) * 16 + colB) * 128 + kc * 32 + q * 8;
          WB[i][kc] = pack8(*(const float4*)r, *(const float4*)(r + 4));
        }
    }
  }
  f32x4 b1v[2];
  const float* p0base[2];
#pragma unroll
  for (int i = 0; i < 2; ++i) {
    int nb = (wl * 2 + i) * 16 + q * 4;
    if (!isL0) {
      b1v[i] = (f32x4){bih1[nb] + bhh1[nb], bih1[nb + 1] + bhh1[nb + 1],
                       bih1[nb + 2] + bhh1[nb + 2], bih1[nb + 3] + bhh1[nb + 3]};
    } else {
      b1v[i] = (f32x4){0.f, 0.f, 0.f, 0.f};
    }
    p0base[i] = P0 + (size_t)(b0 + colB) * 512 * 128 + nb;
  }
  float4 pp0[2], pp1[2];
  if (isL0) {
#pragma unroll
    for (int i = 0; i < 2; ++i) {
      pp0[i] = *(const float4*)(p0base[i]);
      pp1[i] = *(const float4*)(p0base[i] + 128);
    }
  }
  __syncthreads();

  for (int s2 = 0; s2 < 512; s2 += 2) {
    K2STEP(s2, pp0);
    K2STEP(s2 + 1, pp1);
  }
  K2STEP(512, pp0);  // epilogue: L1 computes t=511
}

// ------------------------- K3 v12: edge RNN, dual-group, operand-swapped.
// v12: P1's h1-part (reads n1rd = PREVIOUS step's n1, valid before bar A)
// moved into phase 0 — overlaps with P0 and halves the post-bar-A dependent
// chain. Phase 1 = P1's n0-part only.
#define K3_A(g) ((_Float16*)(sm + (g) * 8192))
#define K3_R(g, i) ((_Float16*)(sm + 16384 + ((g) * 3 + (i)) * 16384))
#define K3_PS(g) ((float*)(sm + 114688 + (g) * 1024))
#define LDSTOT 116736

__global__ __launch_bounds__(512, 2) void k3_edge_f16(
    const float* __restrict__ Y, const unsigned short* __restrict__ Wf,
    const float* __restrict__ bih0, const float* __restrict__ bhh0,
    const float* __restrict__ bih1, const float* __restrict__ bhh1,
    const float* __restrict__ clsW, const float* __restrict__ clsb,
    float* __restrict__ adj) {
  extern __shared__ char sm[];
  const int tid = threadIdx.x;
  const int w = tid >> 6, l = tid & 63;
  const int mg = w & 1, ng = w >> 1;
  const int colL = l & 15, q = l >> 4;
  const int node0 = blockIdx.x * 128;

  // init: A(g)=0, R(g,2)=0 (n1rd at step 0), R(g,0)=f16(Y) swizzled
  for (int i = tid; i < 4096; i += 512) ((unsigned*)sm)[i] = 0u;
  for (int i = tid; i < 4096; i += 512) {
    ((unsigned*)K3_R(0, 2))[i] = 0u;
    ((unsigned*)K3_R(1, 2))[i] = 0u;
  }
  for (int i = tid; i < 16384; i += 512) {
    int nn = i >> 7, k = i & 127;
    float v = Y[(size_t)(node0 + nn) * 128 + k];
    K3_R(nn >> 6, 0)[sw(nn & 63, k, 128)] = (_Float16)v;
  }

  f16x8 Wr[2][14];
#pragma unroll
  for (int nt = 0; nt < 2; ++nt)
#pragma unroll
    for (int kc = 0; kc < 14; ++kc)
      Wr[nt][kc] =
          ((const f16x8*)Wf)[(size_t)(((2 * ng + nt) * 14) + kc) * 64 + l];

  // per-lane constants in D layout: lane covers feats f0..f0+3 per nt
  f32x4 b0v[2], b1v[2];
  h2 cw2[2][2];
#pragma unroll
  for (int nt = 0; nt < 2; ++nt) {
    int f0 = (2 * ng + nt) * 16 + q * 4;
    b0v[nt] = (f32x4){bih0[f0] + bhh0[f0], bih0[f0 + 1] + bhh0[f0 + 1],
                      bih0[f0 + 2] + bhh0[f0 + 2], bih0[f0 + 3] + bhh0[f0 + 3]};
    b1v[nt] = (f32x4){bih1[f0] + bhh1[f0], bih1[f0 + 1] + bhh1[f0 + 1],
                      bih1[f0 + 2] + bhh1[f0 + 2], bih1[f0 + 3] + bhh1[f0 + 3]};
    cw2[nt][0].x = (_Float16)clsW[f0];
    cw2[nt][0].y = (_Float16)clsW[f0 + 1];
    cw2[nt][1].x = (_Float16)clsW[f0 + 2];
    cw2[nt][1].y = (_Float16)clsW[f0 + 3];
  }
  const float cbias = clsb[0];
  int mval[2];
  mval[0] = min(((node0 + 0) & 511) + l, 64);
  mval[1] = min(((node0 + 64) & 511) + l, 64);

  // step-invariant write offsets (granule-swizzled; f0&7 in {0,4} -> 8B align)
  int woff[2][2];  // [mt][nt]
#pragma unroll
  for (int mt = 0; mt < 2; ++mt)
#pragma unroll
    for (int nt = 0; nt < 2; ++nt) {
      int node = mg * 32 + mt * 16 + colL;
      int f0 = (2 * ng + nt) * 16 + q * 4;
      woff[mt][nt] =
          node * 128 + ((((f0 >> 3) ^ (node & 7)) << 3) | (f0 & 7));
    }

  __syncthreads();

  int ba = 0, bbv = 1, bc = 2;  // rotation indices (uniform)
  for (int step = 0; step < 64; ++step) {
    _Float16* p_n0rd[2] = {K3_R(0, ba), K3_R(1, ba)};
    _Float16* p_n0wr[2] = {K3_R(0, bbv), K3_R(1, bbv)};
    _Float16* p_n1rd[2] = {K3_R(0, bc), K3_R(1, bc)};
    _Float16* p_n1wr[2] = {K3_R(0, ba), K3_R(1, ba)};

    // ===== PHASE 0: P0 (all of it) + P1's h1-part (prev-step data)
    f32x4 acc[2][2][2];   // P0 accumulators [g][mt][nt]
    f32x4 acc2[2][2][2];  // P1 accumulators (h1-part here, n0-part phase 1)
#pragma unroll
    for (int g = 0; g < 2; ++g)
#pragma unroll
      for (int mt = 0; mt < 2; ++mt)
#pragma unroll
        for (int nt = 0; nt < 2; ++nt) {
          acc[g][mt][nt] = b0v[nt];
          acc2[g][mt][nt] = b1v[nt];
        }
    // P0 h0-part (K=128)
#pragma unroll
    for (int kc = 0; kc < 4; ++kc) {
      int gk = kc * 4 + q;
      f16x8 bh[2][2];
#pragma unroll
      for (int g = 0; g < 2; ++g)
#pragma unroll
        for (int mt = 0; mt < 2; ++mt) {
          int row = mg * 32 + mt * 16 + colL;
          bh[g][mt] =
              *(const f16x8*)&p_n0rd[g][row * 128 + ((gk ^ (row & 7)) << 3)];
        }
#pragma unroll
      for (int g = 0; g < 2; ++g)
#pragma unroll
        for (int mt = 0; mt < 2; ++mt)
#pragma unroll
          for (int nt = 0; nt < 2; ++nt)
            acc[g][mt][nt] = MFMAH(Wr[nt][2 + kc], bh[g][mt], acc[g][mt][nt]);
    }
    // P1 h1-part (reads n1rd: previous step's n1 — no bar needed)
#pragma unroll
    for (int kc = 4; kc < 8; ++kc) {
      int gk = (kc & 3) * 4 + q;
      f16x8 bh[2][2];
#pragma unroll
      for (int g = 0; g < 2; ++g)
#pragma unroll
        for (int mt = 0; mt < 2; ++mt) {
          int row = mg * 32 + mt * 16 + colL;
          bh[g][mt] =
              *(const f16x8*)&p_n1rd[g][row * 128 + ((gk ^ (row & 7)) << 3)];
        }
#pragma unroll
      for (int g = 0; g < 2; ++g)
#pragma unroll
        for (int mt = 0; mt < 2; ++mt)
#pragma unroll
          for (int nt = 0; nt < 2; ++nt)
            acc2[g][mt][nt] =
                MFMAH(Wr[nt][6 + kc], bh[g][mt], acc2[g][mt][nt]);
    }
    // P0 A-part (cols >= step are zero: skip chunks exactly)
    if (step > 0) {
      {
        int gk = q;
        f16x8 bh[2][2];
#pragma unroll
        for (int g = 0; g < 2; ++g)
#pragma unroll
          for (int mt = 0; mt < 2; ++mt) {
            int row = mg * 32 + mt * 16 + colL;
            bh[g][mt] =
                *(const f16x8*)&K3_A(g)[row * 64 + ((gk ^ (row & 7)) << 3)];
          }
#pragma unroll
        for (int g = 0; g < 2; ++g)
#pragma unroll
          for (int mt = 0; mt < 2; ++mt)
#pragma unroll
            for (int nt = 0; nt < 2; ++nt)
              acc[g][mt][nt] = MFMAH(Wr[nt][0], bh[g][mt], acc[g][mt][nt]);
      }
      if (step > 32) {
        int gk = 4 + q;
        f16x8 bh[2][2];
#pragma unroll
        for (int g = 0; g < 2; ++g)
#pragma unroll
          for (int mt = 0; mt < 2; ++mt) {
            int row = mg * 32 + mt * 16 + colL;
            bh[g][mt] =
                *(const f16x8*)&K3_A(g)[row * 64 + ((gk ^ (row & 7)) << 3)];
          }
#pragma unroll
        for (int g = 0; g < 2; ++g)
#pragma unroll
          for (int mt = 0; mt < 2; ++mt)
#pragma unroll
            for (int nt = 0; nt < 2; ++nt)
              acc[g][mt][nt] = MFMAH(Wr[nt][1], bh[g][mt], acc[g][mt][nt]);
      }
    }
    // P0 epilogue: tanh + aligned uint2 writes
#pragma unroll
    for (int g = 0; g < 2; ++g)
#pragma unroll
      for (int mt = 0; mt < 2; ++mt)
#pragma unroll
        for (int nt = 0; nt < 2; ++nt) {
          float t0 = fast_tanh(acc[g][mt][nt][0]);
          float t1 = fast_tanh(acc[g][mt][nt][1]);
          float t2 = fast_tanh(acc[g][mt][nt][2]);
          float t3 = fast_tanh(acc[g][mt][nt][3]);
          h2 lo = {(_Float16)t0, (_Float16)t1};
          h2 hi = {(_Float16)t2, (_Float16)t3};
          uint2 u = {__builtin_bit_cast(unsigned, lo),
                     __builtin_bit_cast(unsigned, hi)};
          *(uint2*)&p_n0wr[g][woff[mt][nt]] = u;
        }
    __syncthreads();  // bar A: n0 complete

    // ===== PHASE 1: P1's n0-part only (short dependent chain)
#pragma unroll
    for (int kc = 0; kc < 4; ++kc) {
      int gk = kc * 4 + q;
      f16x8 bh[2][2];
#pragma unroll
      for (int g = 0; g < 2; ++g)
#pragma unroll
        for (int mt = 0; mt < 2; ++mt) {
          int row = mg * 32 + mt * 16 + colL;
          bh[g][mt] =
              *(const f16x8*)&p_n0wr[g][row * 128 + ((gk ^ (row & 7)) << 3)];
        }
#pragma unroll
      for (int g = 0; g < 2; ++g)
#pragma unroll
        for (int mt = 0; mt < 2; ++mt)
#pragma unroll
          for (int nt = 0; nt < 2; ++nt)
            acc2[g][mt][nt] =
                MFMAH(Wr[nt][6 + kc], bh[g][mt], acc2[g][mt][nt]);
    }
    float paf[2][2];  // [g][mt] cls partial for node
#pragma unroll
    for (int g = 0; g < 2; ++g)
#pragma unroll
      for (int mt = 0; mt < 2; ++mt) paf[g][mt] = 0.f;
#pragma unroll
    for (int g = 0; g < 2; ++g)
#pragma unroll
      for (int mt = 0; mt < 2; ++mt)
#pragma unroll
        for (int nt = 0; nt < 2; ++nt) {
          float t0 = fast_tanh(acc2[g][mt][nt][0]);
          float t1 = fast_tanh(acc2[g][mt][nt][1]);
          float t2 = fast_tanh(acc2[g][mt][nt][2]);
          float t3 = fast_tanh(acc2[g][mt][nt][3]);
          h2 lo = {(_Float16)t0, (_Float16)t1};
          h2 hi = {(_Float16)t2, (_Float16)t3};
          paf[g][mt] = FDOT2(cw2[nt][0], lo, paf[g][mt]);
          paf[g][mt] = FDOT2(cw2[nt][1], hi, paf[g][mt]);
          uint2 u = {__builtin_bit_cast(unsigned, lo),
                     __builtin_bit_cast(unsigned, hi)};
          *(uint2*)&p_n1wr[g][woff[mt][nt]] = u;
        }
    // reduce cls partials over q (lanes +-16, +-32 share the node)
#pragma unroll
    for (int g = 0; g < 2; ++g)
#pragma unroll
      for (int mt = 0; mt < 2; ++mt) {
        float s = paf[g][mt];
        s += __shfl_xor(s, 16);
        s += __shfl_xor(s, 32);
        paf[g][mt] = s;
      }
    if (q == 0) {
#pragma unroll
      for (int g = 0; g < 2; ++g)
#pragma unroll
        for (int mt = 0; mt < 2; ++mt)
          K3_PS(g)[ng * 64 + mg * 32 + mt * 16 + colL] = paf[g][mt];
    }
    __syncthreads();  // bar B: psum + n1 complete

    // ===== cls: all waves redundantly compute both groups' sigmoids.
    {
      float* ps0 = K3_PS(0);
      float* ps1 = K3_PS(1);
      float s0 = cbias + ps0[l] + ps0[64 + l] + ps0[128 + l] + ps0[192 + l];
      float s1 = cbias + ps1[l] + ps1[64 + l] + ps1[128 + l] + ps1[192 + l];
      float sg0 = fast_sigmoid(s0);
      float sg1 = fast_sigmoid(s1);
      int aidx = l * 64 + ((((step >> 3) ^ (l & 7)) << 3) | (step & 7));
      if (step < mval[0]) K3_A(0)[aidx] = (_Float16)sg0;
      if (step < mval[1]) K3_A(1)[aidx] = (_Float16)sg1;
    }
    int tmp = ba; ba = bbv; bbv = bc; bc = tmp;
  }
  __syncthreads();

  // ---- epilogue: write both groups' FULL 512x64 adj tiles, coalesced.
#pragma unroll
  for (int g = 0; g < 2; ++g) {
    const int qd = l & 15;
    const int rg4 = l >> 4;
    const int node0g = node0 + g * 64;
    const int ii0 = node0g & 511;
    const int badj = node0g >> 9;
    _Float16* Ag = K3_A(g);
    for (int rb = 0; rb < 64; rb += 4) {
      int r = w * 64 + rb + rg4;
      float4 v;
      float* vp = (float*)&v;
#pragma unroll
      for (int c = 0; c < 4; ++c) {
        int n = qd * 4 + c;
        int ii = ii0 + n;
        int base = (ii - 64 > 0) ? ii - 64 : 0;
        int mv = min(ii, 64);
        int k = r - base;
        float val = 0.f;
        if (k >= 0 && k < mv) val = (float)Ag[sw(n, k, 64)];
        vp[c] = val;
      }
      *(float4*)&adj[((size_t)badj * 512 + r) * 512 + ii0 + qd * 4] = v;
    }
  }
}

extern "C" void kernel_launch(void* const* d_in, const int* in_sizes, int n_in,
                              void* d_out, int out_size, void* d_ws,
                              size_t ws_size, hipStream_t stream) {
  const float* x = (const float*)d_in[0];
  const int* mask = (const int*)d_in[1];
  const float* gWih0 = (const float*)d_in[2];
  const float* gWhh0 = (const float*)d_in[3];
  const float* gbih0 = (const float*)d_in[4];
  const float* gbhh0 = (const float*)d_in[5];
  const float* gWih1 = (const float*)d_in[6];
  const float* gWhh1 = (const float*)d_in[7];
  const float* gbih1 = (const float*)d_in[8];
  const float* gbhh1 = (const float*)d_in[9];
  const float* eWih0 = (const float*)d_in[10];
  const float* eWhh0 = (const float*)d_in[11];
  const float* ebih0 = (const float*)d_in[12];
  const float* ebhh0 = (const float*)d_in[13];
  const float* eWih1 = (const float*)d_in[14];
  const float* eWhh1 = (const float*)d_in[15];
  const float* ebih1 = (const float*)d_in[16];
  const float* ebhh1 = (const float*)d_in[17];
  const float* clsW = (const float*)d_in[18];
  const float* clsb = (const float*)d_in[19];
  float* out = (float*)d_out;
  float* Y = out;
  float* adj = out + YSZ;
  float* P0 = adj;  // scratch overlay in adj region; k3 overwrites all of adj

  unsigned short* Wf = (unsigned short*)d_ws;
  hipLaunchKernelGGL(k0_prep, dim3(28), dim3(256), 0, stream, eWih0, eWhh0,
                     eWih1, eWhh1, Wf);
  hipLaunchKernelGGL(k1_gemm, dim3(256), dim3(256), 0, stream, x, gWih0,
                     gbih0, gbhh0, P0);
  hipLaunchKernelGGL(k2_v10, dim3(4), dim3(512), 0, stream, P0, gWhh0, gWih1,
                     gWhh1, gbih1, gbhh1, mask, Y);
  hipFuncSetAttribute(reinterpret_cast<const void*>(k3_edge_f16),
                      hipFuncAttributeMaxDynamicSharedMemorySize, LDSTOT);
  hipLaunchKernelGGL(k3_edge_f16, dim3(256), dim3(512), LDSTOT, stream, Y,
                     Wf, ebih0, ebhh0, ebih1, ebhh1, clsW, clsb, adj);
}

// Round 15
// 576.198 us; speedup vs baseline: 1.0439x; 1.0439x over previous
//
#include <hip/hip_runtime.h>

#define B_ 64
#define S_ 512
#define D_ 256
#define H_ 128
#define M_ 64
#define N_ (B_ * S_)                 // 32768 nodes
#define YSZ ((size_t)N_ * H_)        // 4194304 floats
#define ADJSZ ((size_t)B_ * S_ * S_) // 16777216 floats

typedef __attribute__((ext_vector_type(8))) _Float16 f16x8;
typedef __attribute__((ext_vector_type(2))) _Float16 h2;
typedef __attribute__((ext_vector_type(4))) float f32x4;

#define MFMAH(a, b, c) __builtin_amdgcn_mfma_f32_16x16x32_f16(a, b, c, 0, 0, 0)

// LDS-only barrier (k2): __syncthreads() drains vmcnt(0) too.
#define BARL() asm volatile("s_waitcnt lgkmcnt(0)\n\ts_barrier" ::: "memory")

#if __has_builtin(__builtin_amdgcn_fdot2)
#define FDOT2(a, b, c) __builtin_amdgcn_fdot2((a), (b), (c), false)
#else
__device__ __forceinline__ float FDOT2(h2 a, h2 b, float c) {
  return c + (float)a.x * (float)b.x + (float)a.y * (float)b.y;
}
#endif

// weight frag store: 8 n-tiles x 14 k-chunks, 64 lanes x 16B each (f16)
#define WFRAGS (8 * 14)
#define WBYTES ((size_t)WFRAGS * 64 * 16)  // 114688

// Clamp-free: e^{2x} overflow -> rcp(inf)=0 -> tanh=+1 exactly; e->0 -> -1.
__device__ __forceinline__ float fast_tanh(float x) {
  float e = __builtin_amdgcn_exp2f(x * 2.8853900817779268f);
  float r = __builtin_amdgcn_rcpf(e + 1.0f);
  return fmaf(-2.0f, r, 1.0f);
}
__device__ __forceinline__ float fast_sigmoid(float x) {
  float e = __builtin_amdgcn_exp2f(x * -1.4426950408889634f);
  return __builtin_amdgcn_rcpf(1.0f + e);
}

// element index in a [rows][Kc] f16 array, XOR-swizzled 16B (8-elem) granules
__device__ __forceinline__ int sw(int row, int col, int Kc) {
  return row * Kc + ((((col >> 3) ^ (row & 7)) << 3) | (col & 7));
}
// granule-index form for [16][128] state arrays (g = 8-elem granule 0..15)
__device__ __forceinline__ int swu(int row, int g) {
  return row * 128 + (((g ^ (row & 7)) << 3));
}

__device__ __forceinline__ f16x8 pack8(float4 a, float4 b) {
  f16x8 r;
  r[0] = (_Float16)a.x; r[1] = (_Float16)a.y;
  r[2] = (_Float16)a.z; r[3] = (_Float16)a.w;
  r[4] = (_Float16)b.x; r[5] = (_Float16)b.y;
  r[6] = (_Float16)b.z; r[7] = (_Float16)b.w;
  return r;
}

// ---------------- K0: pack f16 weight fragments (native MFMA frag order;
// layout is symmetric for A and B operands: row/col = lane&15, k=(lane>>4)*8)
__global__ __launch_bounds__(256) void k0_prep(
    const float* __restrict__ eWih0, const float* __restrict__ eWhh0,
    const float* __restrict__ eWih1, const float* __restrict__ eWhh1,
    unsigned short* __restrict__ Wf) {
  int t = blockIdx.x * 256 + threadIdx.x;
  if (t >= WFRAGS * 64) return;
  int fid = t >> 6, lane = t & 63;
  int ntg = fid / 14, kc = fid % 14;
  int j = ntg * 16 + (lane & 15);
  int kbase = (kc < 6 ? kc : kc - 6) * 32 + (lane >> 4) * 8;
  unsigned pk[4];
#pragma unroll
  for (int ii = 0; ii < 4; ++ii) {
    unsigned p2 = 0;
#pragma unroll
    for (int s = 0; s < 2; ++s) {
      int k = kbase + ii * 2 + s;
      float wv;
      if (kc < 6)
        wv = (k < 64) ? eWih0[j * 64 + k] : eWhh0[j * 128 + (k - 64)];
      else
        wv = (k < 128) ? eWih1[j * 128 + k] : eWhh1[j * 128 + (k - 128)];
      _Float16 h = (_Float16)wv;
      unsigned short us = *(unsigned short*)&h;
      p2 |= ((unsigned)us) << (16 * s);
    }
    pk[ii] = p2;
  }
  ((uint4*)Wf)[fid * 64 + lane] = make_uint4(pk[0], pk[1], pk[2], pk[3]);
}

// ------------- K1 v2: P0 = x @ Wih0^T + (bih0+bhh0), f16 MFMA (operand-swap
// D = W x X^T, same pattern as k3). Old f32-VALU k1 ran at 39% vector peak
// (~35us); MFMA + f16-staged X -> memory-bound ~10us. P0 f16 rounding (~1e-3,
// injected once into the L0 chain) is far under the 2e-2 threshold.
__global__ __launch_bounds__(512) void k1_mfma(
    const float* __restrict__ x, const float* __restrict__ W,
    const float* __restrict__ bih, const float* __restrict__ bhh,
    float* __restrict__ P0) {
  __shared__ _Float16 Xs[128 * 256];  // 64 KB, swizzled
  const int tid = threadIdx.x;
  const int w = tid >> 6, l = tid & 63;
  const int colL = l & 15, q = l >> 4;
  const int n0 = blockIdx.x * 128;

  // stage X -> f16 swizzled LDS (wave reads 1 KB contiguous per pass)
  for (int i = tid; i < 8192; i += 512) {
    int nn = i >> 6, f4 = (i & 63) * 4;
    float4 v = *(const float4*)&x[(size_t)(n0 + nn) * 256 + f4];
    h2 lo = {(_Float16)v.x, (_Float16)v.y};
    h2 hi = {(_Float16)v.z, (_Float16)v.w};
    uint2 u = {__builtin_bit_cast(unsigned, lo),
               __builtin_bit_cast(unsigned, hi)};
    *(uint2*)&Xs[sw(nn, f4, 256)] = u;
  }
  // weight A-frags: wave w owns feats w*16..w*16+15, K=256 in 8 chunks
  f16x8 Wr[8];
#pragma unroll
  for (int kc = 0; kc < 8; ++kc) {
    const float* r = W + (w * 16 + colL) * 256 + kc * 32 + q * 8;
    Wr[kc] = pack8(*(const float4*)r, *(const float4*)(r + 4));
  }
  // bias in D layout (lane covers feats f0..f0+3)
  f32x4 bv;
  {
    int f0 = w * 16 + q * 4;
    bv = (f32x4){bih[f0] + bhh[f0], bih[f0 + 1] + bhh[f0 + 1],
                 bih[f0 + 2] + bhh[f0 + 2], bih[f0 + 3] + bhh[f0 + 3]};
  }
  __syncthreads();

  f32x4 acc[8];
#pragma unroll
  for (int mt = 0; mt < 8; ++mt) acc[mt] = bv;
#pragma unroll
  for (int kc = 0; kc < 8; ++kc) {
    int gk = kc * 4 + q;
#pragma unroll
    for (int mt = 0; mt < 8; ++mt) {
      int row = mt * 16 + colL;
      f16x8 bf = *(const f16x8*)&Xs[row * 256 + ((gk ^ (row & 7)) << 3)];
      acc[mt] = MFMAH(Wr[kc], bf, acc[mt]);
    }
  }
  // store: lane -> node n0+mt*16+colL, feats w*16+q*4..+3 (16B aligned)
#pragma unroll
  for (int mt = 0; mt < 8; ++mt) {
    float4 s = {acc[mt][0], acc[mt][1], acc[mt][2], acc[mt][3]};
    *(float4*)&P0[(size_t)(n0 + mt * 16 + colL) * 128 + w * 16 + q * 4] = s;
  }
}

// ------------------------- K2 v10 (stable): batched-MFMA graph RNN, 8 waves;
// waves 0-3 = L0, 4-7 = L1 pipelined; 1 LDS-only barrier/step.
#define K2STEP(S, PP)                                                         \
  {                                                                           \
    if (isL0 && (S) < 512) {                                                  \
      const int rd0 = ((S)&1) ^ 1;                                            \
      f32x4 acc[2];                                                           \
      _Pragma("unroll") for (int i = 0; i < 2; ++i)                           \
          acc[i] = __builtin_bit_cast(f32x4, PP[i]);                          \
      _Pragma("unroll") for (int kc = 0; kc < 4; ++kc) {                      \
        f16x8 bf = *(const f16x8*)&h0s[rd0][swu(colB, kc * 4 + q)];           \
        _Pragma("unroll") for (int i = 0; i < 2; ++i)                         \
            acc[i] = MFMAH(WA[i][kc], bf, acc[i]);                            \
      }                                                                       \
      int tn = ((S) + 2 < 512) ? (S) + 2 : 511;                               \
      _Pragma("unroll") for (int i = 0; i < 2; ++i)                           \
          PP[i] = *(const float4*)(p0base[i] + (size_t)tn * 128);             \
      _Pragma("unroll") for (int i = 0; i < 2; ++i) {                         \
        float v0 = fast_tanh(acc[i][0]), v1 = fast_tanh(acc[i][1]);           \
        float v2 = fast_tanh(acc[i][2]), v3 = fast_tanh(acc[i][3]);           \
        int nb = (wl * 2 + i) * 16 + q * 4;                                   \
        int g = nb >> 3;                                                      \
        int idx = colB * 128 + (((g ^ (colB & 7)) << 3) | (nb & 7));          \
        h2 lo = {(_Float16)v0, (_Float16)v1};                                 \
        h2 hi = {(_Float16)v2, (_Float16)v3};                                 \
        uint2 u = {__builtin_bit_cast(unsigned, lo),                          \
                   __builtin_bit_cast(unsigned, hi)};                         \
        *(uint2*)&h0s[(S)&1][idx] = u;                                        \
      }                                                                       \
    } else if (!isL0 && (S) >= 1) {                                           \
      const int t = (S)-1;                                                    \
      const int rb = t & 1;                                                   \
      f32x4 acc[2], accB[2];                                                  \
      _Pragma("unroll") for (int i = 0; i < 2; ++i) {                         \
        acc[i] = b1v[i];                                                      \
        accB[i] = (f32x4){0.f, 0.f, 0.f, 0.f};                                \
      }                                                                       \
      _Pragma("unroll") for (int kc = 0; kc < 4; ++kc) {                      \
        f16x8 bf = *(const f16x8*)&h0s[rb][swu(colB, kc * 4 + q)];            \
        if ((kc & 1) == 0) {                                                  \
          _Pragma("unroll") for (int i = 0; i < 2; ++i)                       \
              acc[i] = MFMAH(WA[i][kc], bf, acc[i]);                          \
        } else {                                                              \
          _Pragma("unroll") for (int i = 0; i < 2; ++i)                       \
              accB[i] = MFMAH(WA[i][kc], bf, accB[i]);                        \
        }                                                                     \
      }                                                                       \
      _Pragma("unroll") for (int kc = 0; kc < 4; ++kc) {                      \
        f16x8 bf = *(const f16x8*)&h1s[rb ^ 1][swu(colB, kc * 4 + q)];        \
        if ((kc & 1) == 0) {                                                  \
          _Pragma("unroll") for (int i = 0; i < 2; ++i)                       \
              acc[i] = MFMAH(WB[i][kc], bf, acc[i]);                          \
        } else {                                                              \
          _Pragma("unroll") for (int i = 0; i < 2; ++i)                       \
              accB[i] = MFMAH(WB[i][kc], bf, accB[i]);                        \
        }                                                                     \
      }                                                                       \
      float m = mk[colB][t];                                                  \
      _Pragma("unroll") for (int i = 0; i < 2; ++i) {                         \
        f32x4 at = acc[i] + accB[i];                                          \
        float v0 = fast_tanh(at[0]), v1 = fast_tanh(at[1]);                   \
        float v2 = fast_tanh(at[2]), v3 = fast_tanh(at[3]);                   \
        int nb = (wl * 2 + i) * 16 + q * 4;                                   \
        int g = nb >> 3;                                                      \
        int idx = colB * 128 + (((g ^ (colB & 7)) << 3) | (nb & 7));          \
        h2 lo = {(_Float16)v0, (_Float16)v1};                                 \
        h2 hi = {(_Float16)v2, (_Float16)v3};                                 \
        uint2 u = {__builtin_bit_cast(unsigned, lo),                          \
                   __builtin_bit_cast(unsigned, hi)};                         \
        *(uint2*)&h1s[rb][idx] = u;                                           \
        float4 yv = {v0 * m, v1 * m, v2 * m, v3 * m};                         \
        *(float4*)&Y[((size_t)(b0 + colB) * 512 + t) * 128 + nb] = yv;        \
      }                                                                       \
    }                                                                         \
    BARL();                                                                   \
  }

__global__ __launch_bounds__(512, 1) void k2_v10(
    const float* __restrict__ P0, const float* __restrict__ Whh0,
    const float* __restrict__ Wih1, const float* __restrict__ Whh1,
    const float* __restrict__ bih1, const float* __restrict__ bhh1,
    const int* __restrict__ mask, float* __restrict__ Y) {
  __shared__ _Float16 h0s[2][16 * 128];
  __shared__ _Float16 h1s[2][16 * 128];
  __shared__ float mk[16][516];  // padded stride
  const int tid = threadIdx.x;
  const int w = tid >> 6, l = tid & 63;
  const int b0 = blockIdx.x * 16;
  const int colB = l & 15;
  const int q = l >> 4;
  const bool isL0 = (w < 4);
  const int wl = isL0 ? w : (w - 4);

  for (int i = tid; i < 16 * 512; i += 512) {
    int bb = i >> 9, t = i & 511;
    mk[bb][t] = (float)mask[(b0 + bb) * 512 + t];
  }
  for (int i = tid; i < 1024; i += 512) {
    ((unsigned*)&h0s[1][0])[i] = 0u;
    ((unsigned*)&h1s[1][0])[i] = 0u;
  }

  f16x8 WA[2][4];  // L0: Whh0 ; L1: Wih1
  f16x8 WB[2][4];  // L1 only: Whh1
  {
    const float* src = isL0 ? Whh0 : Wih1;
#pragma unroll
    for (int i = 0; i < 2; ++i)
#pragma unroll
      for (int kc = 0; kc < 4; ++kc) {
        const float* r =
            src + ((wl * 2 + i) * 16 + colB) * 128 + kc * 32 + q * 8;
        WA[i][kc] = pack8(*(const float4*)r, *(const float4*)(r + 4));
      }
    if (!isL0) {
#pragma unroll
      for (int i = 0; i < 2; ++i)
#pragma unroll
        for (int kc = 0; kc < 4; ++kc) {
          const float* r =
              Whh1 + ((wl * 2 + i) * 16 + colB) * 128 + kc * 32 + q * 8;
          WB[i][kc] = pack8(*(const float4*)r, *(const float4*)(r + 4));
        }
    }
  }
  f32x4 b1v[2];
  const float* p0base[2];
#pragma unroll
  for (int i = 0; i < 2; ++i) {
    int nb = (wl * 2 + i) * 16 + q * 4;
    if (!isL0) {
      b1v[i] = (f32x4){bih1[nb] + bhh1[nb], bih1[nb + 1] + bhh1[nb + 1],
                       bih1[nb + 2] + bhh1[nb + 2], bih1[nb + 3] + bhh1[nb + 3]};
    } else {
      b1v[i] = (f32x4){0.f, 0.f, 0.f, 0.f};
    }
    p0base[i] = P0 + (size_t)(b0 + colB) * 512 * 128 + nb;
  }
  float4 pp0[2], pp1[2];
  if (isL0) {
#pragma unroll
    for (int i = 0; i < 2; ++i) {
      pp0[i] = *(const float4*)(p0base[i]);
      pp1[i] = *(const float4*)(p0base[i] + 128);
    }
  }
  __syncthreads();

  for (int s2 = 0; s2 < 512; s2 += 2) {
    K2STEP(s2, pp0);
    K2STEP(s2 + 1, pp1);
  }
  K2STEP(512, pp0);  // epilogue: L1 computes t=511
}

// ------------------------- K3 v12 (stable): edge RNN, dual-group,
// operand-swapped; P1's h1-part overlapped into phase 0.
#define K3_A(g) ((_Float16*)(sm + (g) * 8192))
#define K3_R(g, i) ((_Float16*)(sm + 16384 + ((g) * 3 + (i)) * 16384))
#define K3_PS(g) ((float*)(sm + 114688 + (g) * 1024))
#define LDSTOT 116736

__global__ __launch_bounds__(512, 2) void k3_edge_f16(
    const float* __restrict__ Y, const unsigned short* __restrict__ Wf,
    const float* __restrict__ bih0, const float* __restrict__ bhh0,
    const float* __restrict__ bih1, const float* __restrict__ bhh1,
    const float* __restrict__ clsW, const float* __restrict__ clsb,
    float* __restrict__ adj) {
  extern __shared__ char sm[];
  const int tid = threadIdx.x;
  const int w = tid >> 6, l = tid & 63;
  const int mg = w & 1, ng = w >> 1;
  const int colL = l & 15, q = l >> 4;
  const int node0 = blockIdx.x * 128;

  for (int i = tid; i < 4096; i += 512) ((unsigned*)sm)[i] = 0u;
  for (int i = tid; i < 4096; i += 512) {
    ((unsigned*)K3_R(0, 2))[i] = 0u;
    ((unsigned*)K3_R(1, 2))[i] = 0u;
  }
  for (int i = tid; i < 16384; i += 512) {
    int nn = i >> 7, k = i & 127;
    float v = Y[(size_t)(node0 + nn) * 128 + k];
    K3_R(nn >> 6, 0)[sw(nn & 63, k, 128)] = (_Float16)v;
  }

  f16x8 Wr[2][14];
#pragma unroll
  for (int nt = 0; nt < 2; ++nt)
#pragma unroll
    for (int kc = 0; kc < 14; ++kc)
      Wr[nt][kc] =
          ((const f16x8*)Wf)[(size_t)(((2 * ng + nt) * 14) + kc) * 64 + l];

  f32x4 b0v[2], b1v[2];
  h2 cw2[2][2];
#pragma unroll
  for (int nt = 0; nt < 2; ++nt) {
    int f0 = (2 * ng + nt) * 16 + q * 4;
    b0v[nt] = (f32x4){bih0[f0] + bhh0[f0], bih0[f0 + 1] + bhh0[f0 + 1],
                      bih0[f0 + 2] + bhh0[f0 + 2], bih0[f0 + 3] + bhh0[f0 + 3]};
    b1v[nt] = (f32x4){bih1[f0] + bhh1[f0], bih1[f0 + 1] + bhh1[f0 + 1],
                      bih1[f0 + 2] + bhh1[f0 + 2], bih1[f0 + 3] + bhh1[f0 + 3]};
    cw2[nt][0].x = (_Float16)clsW[f0];
    cw2[nt][0].y = (_Float16)clsW[f0 + 1];
    cw2[nt][1].x = (_Float16)clsW[f0 + 2];
    cw2[nt][1].y = (_Float16)clsW[f0 + 3];
  }
  const float cbias = clsb[0];
  int mval[2];
  mval[0] = min(((node0 + 0) & 511) + l, 64);
  mval[1] = min(((node0 + 64) & 511) + l, 64);

  int woff[2][2];  // [mt][nt] step-invariant write offsets
#pragma unroll
  for (int mt = 0; mt < 2; ++mt)
#pragma unroll
    for (int nt = 0; nt < 2; ++nt) {
      int node = mg * 32 + mt * 16 + colL;
      int f0 = (2 * ng + nt) * 16 + q * 4;
      woff[mt][nt] =
          node * 128 + ((((f0 >> 3) ^ (node & 7)) << 3) | (f0 & 7));
    }

  __syncthreads();

  int ba = 0, bbv = 1, bc = 2;
  for (int step = 0; step < 64; ++step) {
    _Float16* p_n0rd[2] = {K3_R(0, ba), K3_R(1, ba)};
    _Float16* p_n0wr[2] = {K3_R(0, bbv), K3_R(1, bbv)};
    _Float16* p_n1rd[2] = {K3_R(0, bc), K3_R(1, bc)};
    _Float16* p_n1wr[2] = {K3_R(0, ba), K3_R(1, ba)};

    // ===== PHASE 0: P0 (all) + P1's h1-part (prev-step data)
    f32x4 acc[2][2][2];
    f32x4 acc2[2][2][2];
#pragma unroll
    for (int g = 0; g < 2; ++g)
#pragma unroll
      for (int mt = 0; mt < 2; ++mt)
#pragma unroll
        for (int nt = 0; nt < 2; ++nt) {
          acc[g][mt][nt] = b0v[nt];
          acc2[g][mt][nt] = b1v[nt];
        }
#pragma unroll
    for (int kc = 0; kc < 4; ++kc) {
      int gk = kc * 4 + q;
      f16x8 bh[2][2];
#pragma unroll
      for (int g = 0; g < 2; ++g)
#pragma unroll
        for (int mt = 0; mt < 2; ++mt) {
          int row = mg * 32 + mt * 16 + colL;
          bh[g][mt] =
              *(const f16x8*)&p_n0rd[g][row * 128 + ((gk ^ (row & 7)) << 3)];
        }
#pragma unroll
      for (int g = 0; g < 2; ++g)
#pragma unroll
        for (int mt = 0; mt < 2; ++mt)
#pragma unroll
          for (int nt = 0; nt < 2; ++nt)
            acc[g][mt][nt] = MFMAH(Wr[nt][2 + kc], bh[g][mt], acc[g][mt][nt]);
    }
#pragma unroll
    for (int kc = 4; kc < 8; ++kc) {
      int gk = (kc & 3) * 4 + q;
      f16x8 bh[2][2];
#pragma unroll
      for (int g = 0; g < 2; ++g)
#pragma unroll
        for (int mt = 0; mt < 2; ++mt) {
          int row = mg * 32 + mt * 16 + colL;
          bh[g][mt] =
              *(const f16x8*)&p_n1rd[g][row * 128 + ((gk ^ (row & 7)) << 3)];
        }
#pragma unroll
      for (int g = 0; g < 2; ++g)
#pragma unroll
        for (int mt = 0; mt < 2; ++mt)
#pragma unroll
          for (int nt = 0; nt < 2; ++nt)
            acc2[g][mt][nt] =
                MFMAH(Wr[nt][6 + kc], bh[g][mt], acc2[g][mt][nt]);
    }
    if (step > 0) {
      {
        int gk = q;
        f16x8 bh[2][2];
#pragma unroll
        for (int g = 0; g < 2; ++g)
#pragma unroll
          for (int mt = 0; mt < 2; ++mt) {
            int row = mg * 32 + mt * 16 + colL;
            bh[g][mt] =
                *(const f16x8*)&K3_A(g)[row * 64 + ((gk ^ (row & 7)) << 3)];
          }
#pragma unroll
        for (int g = 0; g < 2; ++g)
#pragma unroll
          for (int mt = 0; mt < 2; ++mt)
#pragma unroll
            for (int nt = 0; nt < 2; ++nt)
              acc[g][mt][nt] = MFMAH(Wr[nt][0], bh[g][mt], acc[g][mt][nt]);
      }
      if (step > 32) {
        int gk = 4 + q;
        f16x8 bh[2][2];
#pragma unroll
        for (int g = 0; g < 2; ++g)
#pragma unroll
          for (int mt = 0; mt < 2; ++mt) {
            int row = mg * 32 + mt * 16 + colL;
            bh[g][mt] =
                *(const f16x8*)&K3_A(g)[row * 64 + ((gk ^ (row & 7)) << 3)];
          }
#pragma unroll
        for (int g = 0; g < 2; ++g)
#pragma unroll
          for (int mt = 0; mt < 2; ++mt)
#pragma unroll
            for (int nt = 0; nt < 2; ++nt)
              acc[g][mt][nt] = MFMAH(Wr[nt][1], bh[g][mt], acc[g][mt][nt]);
      }
    }
#pragma unroll
    for (int g = 0; g < 2; ++g)
#pragma unroll
      for (int mt = 0; mt < 2; ++mt)
#pragma unroll
        for (int nt = 0; nt < 2; ++nt) {
          float t0 = fast_tanh(acc[g][mt][nt][0]);
          float t1 = fast_tanh(acc[g][mt][nt][1]);
          float t2 = fast_tanh(acc[g][mt][nt][2]);
          float t3 = fast_tanh(acc[g][mt][nt][3]);
          h2 lo = {(_Float16)t0, (_Float16)t1};
          h2 hi = {(_Float16)t2, (_Float16)t3};
          uint2 u = {__builtin_bit_cast(unsigned, lo),
                     __builtin_bit_cast(unsigned, hi)};
          *(uint2*)&p_n0wr[g][woff[mt][nt]] = u;
        }
    __syncthreads();  // bar A: n0 complete

    // ===== PHASE 1: P1's n0-part only
#pragma unroll
    for (int kc = 0; kc < 4; ++kc) {
      int gk = kc * 4 + q;
      f16x8 bh[2][2];
#pragma unroll
      for (int g = 0; g < 2; ++g)
#pragma unroll
        for (int mt = 0; mt < 2; ++mt) {
          int row = mg * 32 + mt * 16 + colL;
          bh[g][mt] =
              *(const f16x8*)&p_n0wr[g][row * 128 + ((gk ^ (row & 7)) << 3)];
        }
#pragma unroll
      for (int g = 0; g < 2; ++g)
#pragma unroll
        for (int mt = 0; mt < 2; ++mt)
#pragma unroll
          for (int nt = 0; nt < 2; ++nt)
            acc2[g][mt][nt] =
                MFMAH(Wr[nt][6 + kc], bh[g][mt], acc2[g][mt][nt]);
    }
    float paf[2][2];
#pragma unroll
    for (int g = 0; g < 2; ++g)
#pragma unroll
      for (int mt = 0; mt < 2; ++mt) paf[g][mt] = 0.f;
#pragma unroll
    for (int g = 0; g < 2; ++g)
#pragma unroll
      for (int mt = 0; mt < 2; ++mt)
#pragma unroll
        for (int nt = 0; nt < 2; ++nt) {
          float t0 = fast_tanh(acc2[g][mt][nt][0]);
          float t1 = fast_tanh(acc2[g][mt][nt][1]);
          float t2 = fast_tanh(acc2[g][mt][nt][2]);
          float t3 = fast_tanh(acc2[g][mt][nt][3]);
          h2 lo = {(_Float16)t0, (_Float16)t1};
          h2 hi = {(_Float16)t2, (_Float16)t3};
          paf[g][mt] = FDOT2(cw2[nt][0], lo, paf[g][mt]);
          paf[g][mt] = FDOT2(cw2[nt][1], hi, paf[g][mt]);
          uint2 u = {__builtin_bit_cast(unsigned, lo),
                     __builtin_bit_cast(unsigned, hi)};
          *(uint2*)&p_n1wr[g][woff[mt][nt]] = u;
        }
#pragma unroll
    for (int g = 0; g < 2; ++g)
#pragma unroll
      for (int mt = 0; mt < 2; ++mt) {
        float s = paf[g][mt];
        s += __shfl_xor(s, 16);
        s += __shfl_xor(s, 32);
        paf[g][mt] = s;
      }
    if (q == 0) {
#pragma unroll
      for (int g = 0; g < 2; ++g)
#pragma unroll
        for (int mt = 0; mt < 2; ++mt)
          K3_PS(g)[ng * 64 + mg * 32 + mt * 16 + colL] = paf[g][mt];
    }
    __syncthreads();  // bar B: psum + n1 complete

    {
      float* ps0 = K3_PS(0);
      float* ps1 = K3_PS(1);
      float s0 = cbias + ps0[l] + ps0[64 + l] + ps0[128 + l] + ps0[192 + l];
      float s1 = cbias + ps1[l] + ps1[64 + l] + ps1[128 + l] + ps1[192 + l];
      float sg0 = fast_sigmoid(s0);
      float sg1 = fast_sigmoid(s1);
      int aidx = l * 64 + ((((step >> 3) ^ (l & 7)) << 3) | (step & 7));
      if (step < mval[0]) K3_A(0)[aidx] = (_Float16)sg0;
      if (step < mval[1]) K3_A(1)[aidx] = (_Float16)sg1;
    }
    int tmp = ba; ba = bbv; bbv = bc; bc = tmp;
  }
  __syncthreads();

#pragma unroll
  for (int g = 0; g < 2; ++g) {
    const int qd = l & 15;
    const int rg4 = l >> 4;
    const int node0g = node0 + g * 64;
    const int ii0 = node0g & 511;
    const int badj = node0g >> 9;
    _Float16* Ag = K3_A(g);
    for (int rb = 0; rb < 64; rb += 4) {
      int r = w * 64 + rb + rg4;
      float4 v;
      float* vp = (float*)&v;
#pragma unroll
      for (int c = 0; c < 4; ++c) {
        int n = qd * 4 + c;
        int ii = ii0 + n;
        int base = (ii - 64 > 0) ? ii - 64 : 0;
        int mv = min(ii, 64);
        int k = r - base;
        float val = 0.f;
        if (k >= 0 && k < mv) val = (float)Ag[sw(n, k, 64)];
        vp[c] = val;
      }
      *(float4*)&adj[((size_t)badj * 512 + r) * 512 + ii0 + qd * 4] = v;
    }
  }
}

extern "C" void kernel_launch(void* const* d_in, const int* in_sizes, int n_in,
                              void* d_out, int out_size, void* d_ws,
                              size_t ws_size, hipStream_t stream) {
  const float* x = (const float*)d_in[0];
  const int* mask = (const int*)d_in[1];
  const float* gWih0 = (const float*)d_in[2];
  const float* gWhh0 = (const float*)d_in[3];
  const float* gbih0 = (const float*)d_in[4];
  const float* gbhh0 = (const float*)d_in[5];
  const float* gWih1 = (const float*)d_in[6];
  const float* gWhh1 = (const float*)d_in[7];
  const float* gbih1 = (const float*)d_in[8];
  const float* gbhh1 = (const float*)d_in[9];
  const float* eWih0 = (const float*)d_in[10];
  const float* eWhh0 = (const float*)d_in[11];
  const float* ebih0 = (const float*)d_in[12];
  const float* ebhh0 = (const float*)d_in[13];
  const float* eWih1 = (const float*)d_in[14];
  const float* eWhh1 = (const float*)d_in[15];
  const float* ebih1 = (const float*)d_in[16];
  const float* ebhh1 = (const float*)d_in[17];
  const float* clsW = (const float*)d_in[18];
  const float* clsb = (const float*)d_in[19];
  float* out = (float*)d_out;
  float* Y = out;
  float* adj = out + YSZ;
  float* P0 = adj;  // scratch overlay in adj region; k3 overwrites all of adj

  unsigned short* Wf = (unsigned short*)d_ws;
  hipLaunchKernelGGL(k0_prep, dim3(28), dim3(256), 0, stream, eWih0, eWhh0,
                     eWih1, eWhh1, Wf);
  hipLaunchKernelGGL(k1_mfma, dim3(256), dim3(512), 0, stream, x, gWih0,
                     gbih0, gbhh0, P0);
  hipLaunchKernelGGL(k2_v10, dim3(4), dim3(512), 0, stream, P0, gWhh0, gWih1,
                     gWhh1, gbih1, gbhh1, mask, Y);
  hipFuncSetAttribute(reinterpret_cast<const void*>(k3_edge_f16),
                      hipFuncAttributeMaxDynamicSharedMemorySize, LDSTOT);
  hipLaunchKernelGGL(k3_edge_f16, dim3(256), dim3(512), LDSTOT, stream, Y,
                     Wf, ebih0, ebhh0, ebih1, ebhh1, clsW, clsb, adj);
}